// Round 2
// baseline (2880.180 us; speedup 1.0000x reference)
//
#include <hip/hip_runtime.h>
#include <hip/hip_bf16.h>

// Problem constants (fixed by setup_inputs)
#define E_N    100000
#define B_N    256
#define TOPK   64
#define NPREV  50000
#define NENT   20000
#define NTIME  2000
#define NREL   200
#define M_OUT  16384   // B_N * TOPK

static __device__ __forceinline__ float sigm(float x){ return 1.f/(1.f+expf(-x)); }

// ---------------------------------------------------------------- utilities
__global__ void zero_kernel(unsigned* __restrict__ p, int n){
  int i = blockIdx.x*256 + threadIdx.x;
  if (i < n) p[i] = 0u;
}

// out[k] = sum_d M[d*ldm + moff + k] * v[d],  k in [0,256), d in [0,256)
__global__ void matT_vec_kernel(const float* __restrict__ M, int ldm, int moff,
                                const float* __restrict__ v, float* __restrict__ out){
  int k = threadIdx.x;
  float acc = 0.f;
  for (int d = 0; d < 256; ++d) acc += M[(size_t)d*ldm + moff + k] * v[d];
  out[k] = acc;
}

// consts[0] = att_1_b[0] + dot(lin_e_ts_b, att_1_w[512:768])
__global__ void c1_kernel(const float* __restrict__ letsb, const float* __restrict__ att1w,
                          const float* __restrict__ att1b, float* __restrict__ consts){
  int lane = threadIdx.x;
  float p = 0.f;
  for (int d = lane; d < 256; d += 64) p += letsb[d]*att1w[512+d];
  for (int o = 32; o > 0; o >>= 1) p += __shfl_down(p, o);
  if (lane == 0) consts[0] = att1b[0] + p;
}

// out[i] = dot(A[i,:256], v)   (one wave per row)
__global__ void rows_dot_kernel(const float* __restrict__ A, const float* __restrict__ v,
                                float* __restrict__ out, int nrows){
  int gid = blockIdx.x*blockDim.x + threadIdx.x;
  int wid = gid >> 6, lane = gid & 63;
  if (wid >= nrows) return;
  const float* row = A + (size_t)wid*256;
  float p = 0.f;
  for (int k = lane; k < 256; k += 64) p += row[k]*v[k];
  for (int o = 32; o > 0; o >>= 1) p += __shfl_down(p, o);
  if (lane == 0) out[wid] = p;
}

// out[row, d + 256*q] = bias[d+256q] + sum_k A[row,k]*Bw[(d+256q)*ldb + boff + k]
// 16 rows per block, thread = output dim d, K = 256.
template<int ND>
__global__ __launch_bounds__(256) void tile_linear(
    const float* __restrict__ A, int lda,
    const float* __restrict__ Bw, int ldb, int boff,
    const float* __restrict__ bias,
    float* __restrict__ out, int ldo, int rows){
  __shared__ float a_s[16][260];
  int tile0 = blockIdx.x*16;
  for (int idx = threadIdx.x; idx < 16*256; idx += 256){
    int i = idx >> 8, k = idx & 255;
    int row = tile0 + i;
    a_s[i][k] = (row < rows) ? A[(size_t)row*lda + k] : 0.f;
  }
  __syncthreads();
  int d = threadIdx.x;
  const float* brow[ND];
  #pragma unroll
  for (int q = 0; q < ND; ++q) brow[q] = Bw + (size_t)(d + 256*q)*ldb + boff;
  float acc[ND][16];
  #pragma unroll
  for (int q = 0; q < ND; ++q){
    float bv = bias ? bias[d + 256*q] : 0.f;
    #pragma unroll
    for (int i = 0; i < 16; ++i) acc[q][i] = bv;
  }
  for (int k = 0; k < 256; k += 4){
    float4 w[ND];
    #pragma unroll
    for (int q = 0; q < ND; ++q) w[q] = *(const float4*)(brow[q] + k);
    #pragma unroll
    for (int i = 0; i < 16; ++i){
      float4 a = *(const float4*)&a_s[i][k];
      #pragma unroll
      for (int q = 0; q < ND; ++q)
        acc[q][i] += w[q].x*a.x + w[q].y*a.y + w[q].z*a.z + w[q].w*a.w;
    }
  }
  #pragma unroll
  for (int i = 0; i < 16; ++i){
    int row = tile0 + i;
    if (row < rows){
      #pragma unroll
      for (int q = 0; q < ND; ++q) out[(size_t)row*ldo + d + 256*q] = acc[q][i];
    }
  }
}

// ---------------------------------------------------------------- CSR by node
__global__ void hist_kernel(const int* __restrict__ facts, int* __restrict__ cnt){
  int e = blockIdx.x*256 + threadIdx.x;
  if (e < E_N) atomicAdd(&cnt[facts[e*6+1]], 1);
}

__global__ void csr_scan_kernel(const int* __restrict__ cnt, int* __restrict__ off,
                                int* __restrict__ cur){
  int lane = threadIdx.x;   // 64 threads, 1 block
  int run = 0;
  for (int base = 0; base < NPREV; base += 64){
    int idx = base + lane;
    int orig = (idx < NPREV) ? cnt[idx] : 0;
    int v = orig;
    for (int o = 1; o < 64; o <<= 1){ int t = __shfl_up(v, o); if (lane >= o) v += t; }
    if (idx < NPREV){ int ex = run + v - orig; off[idx] = ex; cur[idx] = ex; }
    run += __shfl(v, 63);
  }
  if (lane == 0) off[NPREV] = E_N;
}

__global__ void scatter_kernel(const int* __restrict__ facts, int* __restrict__ cur,
                               int* __restrict__ edges){
  int e = blockIdx.x*256 + threadIdx.x;
  if (e < E_N){
    int n = facts[e*6+1];
    int p = atomicAdd(&cur[n], 1);
    edges[p] = e;
  }
}

// ---------------------------------------------------------------- stage 1: attention per edge
// Per block: 16 nodes. gh = hidden_rel[n] @ W_hh^T + b_hh computed in registers,
// then GRU + att2 per edge of those nodes (CSR). att1 from precomputed scalar tables.
__global__ __launch_bounds__(256) void att_kernel(
    const float* __restrict__ hidden_rel,
    const float* __restrict__ w_hh, const float* __restrict__ b_hh,
    const float* __restrict__ gi,   // [NREL][768]
    const float* __restrict__ att2w, const float* __restrict__ att2b,
    const int* __restrict__ facts,
    const int* __restrict__ csr_off, const int* __restrict__ csr_edges,
    const float* __restrict__ qdot, const float* __restrict__ sn_m,
    const float* __restrict__ sr_m, const float* __restrict__ se,
    const float* __restrict__ st,   const float* __restrict__ consts,
    float* __restrict__ attention){
  __shared__ float hrel[16][260];
  __shared__ float a2s[256];
  __shared__ float red[16][17];
  __shared__ int ebase[16], ecnt[16], mc_s;
  int tile0 = blockIdx.x*16;
  for (int idx = threadIdx.x; idx < 16*256; idx += 256){
    int i = idx >> 8, k = idx & 255;
    hrel[i][k] = hidden_rel[(size_t)(tile0+i)*256 + k];
  }
  a2s[threadIdx.x] = att2w[threadIdx.x];
  if (threadIdx.x < 16){
    int n = tile0 + threadIdx.x;
    int o0 = csr_off[n];
    ebase[threadIdx.x] = o0;
    ecnt[threadIdx.x]  = csr_off[n+1] - o0;
  }
  if (threadIdx.x == 0) mc_s = 0;
  __syncthreads();
  if (threadIdx.x < 16) atomicMax(&mc_s, ecnt[threadIdx.x]);

  int g = threadIdx.x >> 4, i = threadIdx.x & 15;
  float ar[16], az[16], an[16];
  #pragma unroll
  for (int m = 0; m < 16; ++m){
    int d = g + 16*m;
    ar[m] = b_hh[d]; az[m] = b_hh[256+d]; an[m] = b_hh[512+d];
  }
  #pragma unroll
  for (int m = 0; m < 16; ++m){
    int d = g + 16*m;
    const float* wr = w_hh + (size_t)d*256;
    const float* wz = w_hh + (size_t)(256+d)*256;
    const float* wn = w_hh + (size_t)(512+d)*256;
    float s0 = 0.f, s1 = 0.f, s2 = 0.f;
    for (int k = 0; k < 256; k += 4){
      float4 a  = *(const float4*)&hrel[i][k];
      float4 w0 = *(const float4*)(wr + k);
      float4 w1 = *(const float4*)(wz + k);
      float4 w2 = *(const float4*)(wn + k);
      s0 += w0.x*a.x + w0.y*a.y + w0.z*a.z + w0.w*a.w;
      s1 += w1.x*a.x + w1.y*a.y + w1.z*a.z + w1.w*a.w;
      s2 += w2.x*a.x + w2.y*a.y + w2.z*a.z + w2.w*a.w;
    }
    ar[m] += s0; az[m] += s1; an[m] += s2;
  }
  __syncthreads();
  int mc = mc_s;
  for (int j = 0; j < mc; ++j){
    bool active = (j < ecnt[i]);
    int e = 0, b = 0, r = 0, t_ = 0, ts_ = 0;
    float partial = 0.f;
    if (active){
      e  = csr_edges[ebase[i] + j];
      b  = facts[e*6+0]; r = facts[e*6+3]; t_ = facts[e*6+4]; ts_ = facts[e*6+5];
      const float* girow = gi + (size_t)r*768;
      #pragma unroll
      for (int m = 0; m < 16; ++m){
        int d = g + 16*m;
        float rg = sigm(girow[d]       + ar[m]);
        float zg = sigm(girow[256+d]   + az[m]);
        float ng = tanhf(girow[512+d]  + rg*an[m]);
        float hp = hrel[i][d];
        float hrn = (1.f - zg)*ng + zg*hp;
        partial += a2s[d]*hrn;
      }
    }
    red[i][g] = partial;
    __syncthreads();
    if (g == 0 && active){
      float s = 0.f;
      #pragma unroll
      for (int gg = 0; gg < 16; ++gg) s += red[i][gg];
      float att2 = sigm(s + att2b[0]);
      float x1 = qdot[b] + sn_m[tile0+i] + sr_m[r] + se[t_] + st[ts_] + consts[0];
      float att1 = sigm(x1);
      attention[e] = 0.5f*(att1 + att2);
    }
    __syncthreads();
  }
}

// ---------------------------------------------------------------- stage 2: per-batch top-64
__global__ __launch_bounds__(256) void topk_kernel(
    const int* __restrict__ facts, const float* __restrict__ attention,
    const float* __restrict__ att_agg,
    int* __restrict__ sel_edge, float* __restrict__ att_norm,
    unsigned* __restrict__ skey, int* __restrict__ Ub){
  __shared__ float sa[512];
  __shared__ int   si[512];
  __shared__ unsigned sk[64];
  __shared__ int cnt;
  int b = blockIdx.x, tid = threadIdx.x;
  sa[tid] = -1.f; sa[tid+256] = -1.f;
  si[tid] = 0x7fffffff; si[tid+256] = 0x7fffffff;
  if (tid == 0) cnt = 0;
  __syncthreads();
  for (int e = tid; e < E_N; e += 256){
    if (facts[e*6] == b){
      int p = atomicAdd(&cnt, 1);
      if (p < 512){ sa[p] = attention[e]; si[p] = e; }
    }
  }
  __syncthreads();
  // bitonic sort: attention desc, edge index asc (matches stable lexsort)
  for (int k = 2; k <= 512; k <<= 1){
    for (int j = k >> 1; j > 0; j >>= 1){
      for (int i0 = tid; i0 < 512; i0 += 256){
        int l = i0 ^ j;
        if (l > i0){
          float ai = sa[i0], al = sa[l];
          int   ii = si[i0], il = si[l];
          bool lFirst = (al > ai) || (al == ai && il < ii);
          bool up = ((i0 & k) == 0);
          if (up ? lFirst : !lFirst){
            sa[i0] = al; sa[l] = ai; si[i0] = il; si[l] = ii;
          }
        }
      }
      __syncthreads();
    }
  }
  // selected 64: raw att * att_agg[n], normalize by per-batch sum
  if (tid < 64){
    int e = si[tid];
    bool valid = (e != 0x7fffffff);
    if (!valid) e = 0;
    int n = facts[e*6+1];
    float a = valid ? sa[tid]*att_agg[n] : 0.f;
    float den = a;
    for (int o = 32; o > 0; o >>= 1) den += __shfl_down(den, o);
    den = __shfl(den, 0);
    float norm = (den != 0.f) ? a/den : 0.f;
    sel_edge[b*64 + tid] = e;
    att_norm[b*64 + tid] = norm;
    int t_ = facts[e*6+4], ts_ = facts[e*6+5];
    unsigned key = (((unsigned)t_) << 11) | (unsigned)ts_;
    sk[tid] = (key << 6) | (unsigned)tid;
  }
  __syncthreads();
  // sort 64 keys ascending ((t,ts) then slot) -- matches jnp.unique row sort per batch
  for (int k = 2; k <= 64; k <<= 1){
    for (int j = k >> 1; j > 0; j >>= 1){
      unsigned nv = 0; bool act = tid < 64;
      if (act){
        unsigned mine = sk[tid], other = sk[tid ^ j];
        bool up = ((tid & k) == 0);
        bool keepmin = (up == ((tid & j) == 0));
        nv = keepmin ? (mine < other ? mine : other) : (mine > other ? mine : other);
      }
      __syncthreads();
      if (act) sk[tid] = nv;
      __syncthreads();
    }
  }
  if (tid < 64){
    unsigned kk = sk[tid];
    skey[b*64 + tid] = kk;
    bool head = (tid == 0) || ((kk >> 6) != (sk[tid-1] >> 6));
    unsigned long long bal = __ballot(head);
    if (tid == 0) Ub[b] = __popcll(bal);
  }
}

__global__ void offs_scan_kernel(const int* __restrict__ Ub, int* __restrict__ offs){
  int lane = threadIdx.x;  // 64 threads, 1 block
  int run = 0;
  for (int base = 0; base < 256; base += 64){
    int orig = Ub[base + lane];
    int v = orig;
    for (int o = 1; o < 64; o <<= 1){ int t = __shfl_up(v, o); if (lane >= o) v += t; }
    offs[base + lane] = run + v - orig;
    run += __shfl(v, 63);
  }
  if (lane == 0) offs[256] = run;
}

__global__ void emit_kernel(const unsigned* __restrict__ skey, const int* __restrict__ offs,
                            int* __restrict__ us, int* __restrict__ tails,
                            float* __restrict__ out_tail){
  int b = blockIdx.x, tid = threadIdx.x;  // block of 64
  unsigned kk = skey[b*64 + tid];
  bool head = (tid == 0) || ((kk >> 6) != (skey[b*64 + tid - 1] >> 6));
  unsigned long long bal = __ballot(head);
  unsigned long long mask_le = (tid == 63) ? ~0ull : ((1ull << (tid+1)) - 1ull);
  int ulocal = __popcll(bal & mask_le) - 1;
  int u = offs[b] + ulocal;
  us[b*64 + tid] = u;
  if (head){
    unsigned key = kk >> 6;
    int t_ = (int)(key >> 11), ts_ = (int)(key & 2047u);
    tails[u*3+0] = b; tails[u*3+1] = t_; tails[u*3+2] = ts_;
    out_tail[u*3+0] = (float)b;
    out_tail[u*3+1] = (float)t_;
    out_tail[u*3+2] = (float)ts_;
  }
}

// ---------------------------------------------------------------- selected-edge vectors
// For the 16384 selected edges (in per-batch sorted order), recompute
// message and hidden_rel_new, premultiplied by normalized attention.
__global__ __launch_bounds__(256) void sel_kernel(
    const unsigned* __restrict__ skey, const int* __restrict__ sel_edge,
    const float* __restrict__ att_norm, const int* __restrict__ facts,
    const float* __restrict__ hidden_node, const float* __restrict__ hidden_rel,
    const float* __restrict__ w_msg, const float* __restrict__ msg_r,
    const float* __restrict__ gi, const float* __restrict__ w_hh,
    const float* __restrict__ b_hh,
    float* __restrict__ msg_sel, float* __restrict__ hrn_sel){
  __shared__ float hn_s[8][260];
  __shared__ float hr_s[8][260];
  __shared__ int n_s[8], r_s[8];
  __shared__ float av_s[8];
  int base = blockIdx.x*8;
  int d = threadIdx.x;
  if (d < 8){
    int gs = base + d;
    int b = gs >> 6, i = gs & 63;
    int j = (int)(skey[(size_t)b*64 + i] & 63u);
    int s = b*64 + j;
    int e = sel_edge[s];
    n_s[d] = facts[e*6+1];
    r_s[d] = facts[e*6+3];
    av_s[d] = att_norm[s];
  }
  __syncthreads();
  for (int idx = d; idx < 8*256; idx += 256){
    int ii = idx >> 8, k = idx & 255;
    int n = n_s[ii];
    hn_s[ii][k] = hidden_node[(size_t)n*256 + k];
    hr_s[ii][k] = hidden_rel[(size_t)n*256 + k];
  }
  __syncthreads();
  const float* wm = w_msg + (size_t)d*512;         // first 256 cols of W_message row d
  const float* wr = w_hh + (size_t)d*256;
  const float* wz = w_hh + (size_t)(256+d)*256;
  const float* wn = w_hh + (size_t)(512+d)*256;
  float sm[8] = {0,0,0,0,0,0,0,0};
  float sr[8] = {0,0,0,0,0,0,0,0};
  float sz[8] = {0,0,0,0,0,0,0,0};
  float sn2[8] = {0,0,0,0,0,0,0,0};
  for (int k = 0; k < 256; k += 4){
    float4 w0 = *(const float4*)(wm + k);
    float4 w1 = *(const float4*)(wr + k);
    float4 w2 = *(const float4*)(wz + k);
    float4 w3 = *(const float4*)(wn + k);
    #pragma unroll
    for (int ii = 0; ii < 8; ++ii){
      float4 a = *(const float4*)&hn_s[ii][k];
      float4 h = *(const float4*)&hr_s[ii][k];
      sm[ii]  += w0.x*a.x + w0.y*a.y + w0.z*a.z + w0.w*a.w;
      sr[ii]  += w1.x*h.x + w1.y*h.y + w1.z*h.z + w1.w*h.w;
      sz[ii]  += w2.x*h.x + w2.y*h.y + w2.z*h.z + w2.w*h.w;
      sn2[ii] += w3.x*h.x + w3.y*h.y + w3.z*h.z + w3.w*h.w;
    }
  }
  float bhr = b_hh[d], bhz = b_hh[256+d], bhn = b_hh[512+d];
  #pragma unroll
  for (int ii = 0; ii < 8; ++ii){
    int r = r_s[ii]; float a = av_s[ii];
    const float* girow = gi + (size_t)r*768;
    float msgv = sm[ii] + msg_r[(size_t)r*256 + d];
    float rg = sigm(girow[d]      + sr[ii] + bhr);
    float zg = sigm(girow[256+d]  + sz[ii] + bhz);
    float ng = tanhf(girow[512+d] + rg*(sn2[ii] + bhn));
    float hrn = (1.f - zg)*ng + zg*hr_s[ii][d];
    size_t o = (size_t)(base + ii)*256 + d;
    msg_sel[o] = a*msgv;
    hrn_sel[o] = a*hrn;
  }
}

// ---------------------------------------------------------------- deterministic segment sums
__global__ __launch_bounds__(256) void segsum_kernel(
    const unsigned* __restrict__ skey, const int* __restrict__ us,
    const float* __restrict__ att_norm,
    const float* __restrict__ msg_sel, const float* __restrict__ hrn_sel,
    float* __restrict__ msg_agg, float* __restrict__ out_hrel,
    float* __restrict__ out_aagg){
  int b = blockIdx.x, d = threadIdx.x;
  float accm = 0.f, acch = 0.f, acca = 0.f;
  int ucur = -1;
  for (int i = 0; i < 64; ++i){
    int u = us[b*64 + i];
    if (u != ucur){
      if (ucur >= 0){
        msg_agg[(size_t)ucur*256 + d] = accm;
        out_hrel[(size_t)ucur*256 + d] = acch;
        if (d == 0) out_aagg[ucur] = acca;
      }
      ucur = u; accm = 0.f; acch = 0.f; acca = 0.f;
    }
    size_t o = (size_t)(b*64 + i)*256 + d;
    accm += msg_sel[o];
    acch += hrn_sel[o];
    int j = (int)(skey[b*64 + i] & 63u);
    acca += att_norm[b*64 + j];
  }
  if (ucur >= 0){
    msg_agg[(size_t)ucur*256 + d] = accm;
    out_hrel[(size_t)ucur*256 + d] = acch;
    if (d == 0) out_aagg[ucur] = acca;
  }
}

// ---------------------------------------------------------------- final linear
// hidden_node_new[u] = [msg_agg[u] | ent_t[t_u]+time_t[ts_u]] @ W_h^T + b_h
__global__ __launch_bounds__(256) void final_kernel(
    const float* __restrict__ msg_agg, const int* __restrict__ tails,
    const float* __restrict__ ent_t, const float* __restrict__ time_t,
    const float* __restrict__ w_h, const float* __restrict__ b_h,
    float* __restrict__ out_hn){
  __shared__ float x_s[16][520];
  int tile0 = blockIdx.x*16;
  for (int idx = threadIdx.x; idx < 16*512; idx += 256){
    int i = idx >> 9, k = idx & 511;
    int u = tile0 + i;
    float v;
    if (k < 256) v = msg_agg[(size_t)u*256 + k];
    else {
      int kk = k - 256;
      v = ent_t[(size_t)tails[u*3+1]*256 + kk] + time_t[(size_t)tails[u*3+2]*256 + kk];
    }
    x_s[i][k] = v;
  }
  __syncthreads();
  int d = threadIdx.x;
  const float* wrow = w_h + (size_t)d*512;
  float bv = b_h[d];
  float acc[16];
  #pragma unroll
  for (int i = 0; i < 16; ++i) acc[i] = bv;
  for (int k = 0; k < 512; k += 4){
    float4 w = *(const float4*)(wrow + k);
    #pragma unroll
    for (int i = 0; i < 16; ++i){
      float4 a = *(const float4*)&x_s[i][k];
      acc[i] += w.x*a.x + w.y*a.y + w.z*a.z + w.w*a.w;
    }
  }
  #pragma unroll
  for (int i = 0; i < 16; ++i)
    out_hn[(size_t)(tile0+i)*256 + d] = acc[i];
}

// ================================================================ launcher
extern "C" void kernel_launch(void* const* d_in, const int* in_sizes, int n_in,
                              void* d_out, int out_size, void* d_ws, size_t ws_size,
                              hipStream_t stream){
  const float* query_emd   = (const float*)d_in[1];
  const int*   facts       = (const int*)  d_in[2];
  const float* ent_emd     = (const float*)d_in[3];
  const float* rel_emd     = (const float*)d_in[4];
  const float* hidden_node = (const float*)d_in[5];
  const float* hidden_rel  = (const float*)d_in[6];
  const float* att_agg     = (const float*)d_in[8];
  const float* time_emd    = (const float*)d_in[9];
  const float* w_msg       = (const float*)d_in[11];
  const float* b_msg       = (const float*)d_in[12];
  const float* att1w       = (const float*)d_in[13];
  const float* att1b       = (const float*)d_in[14];
  const float* att2w       = (const float*)d_in[15];
  const float* att2b       = (const float*)d_in[16];
  const float* w_h         = (const float*)d_in[17];
  const float* b_h         = (const float*)d_in[18];
  const float* lets_w      = (const float*)d_in[19];
  const float* lets_b      = (const float*)d_in[20];
  const float* lrts_w      = (const float*)d_in[21];
  const float* lrts_b      = (const float*)d_in[22];
  const float* w_ih        = (const float*)d_in[25];
  const float* w_hh        = (const float*)d_in[26];
  const float* b_ih        = (const float*)d_in[27];
  const float* b_hh        = (const float*)d_in[28];

  // ---- workspace carve (total ~76 MB)
  char* p = (char*)d_ws;
  auto alloc = [&](size_t bytes) -> void* {
    void* r = (void*)p; p += (bytes + 255) & ~(size_t)255; return r;
  };
  float* attention = (float*)alloc(E_N*4);
  float* qdot   = (float*)alloc(256*4);
  float* sn_m   = (float*)alloc(NPREV*4);
  float* se     = (float*)alloc(NENT*4);
  float* st     = (float*)alloc(NTIME*4);
  float* sr_m   = (float*)alloc(NREL*4);
  float* wm1a   = (float*)alloc(256*4);
  float* ve     = (float*)alloc(256*4);
  float* vts    = (float*)alloc(256*4);
  float* consts = (float*)alloc(8*4);
  float* hr2    = (float*)alloc((size_t)NREL*256*4);
  float* msg_r  = (float*)alloc((size_t)NREL*256*4);
  float* gi     = (float*)alloc((size_t)NREL*768*4);
  float* time_t = (float*)alloc((size_t)NTIME*256*4);
  float* ent_t  = (float*)alloc((size_t)NENT*256*4);
  int* csr_cnt  = (int*)alloc(NPREV*4);
  int* csr_off  = (int*)alloc((NPREV+1)*4);
  int* csr_cur  = (int*)alloc(NPREV*4);
  int* csr_edges= (int*)alloc(E_N*4);
  int* sel_edge = (int*)alloc(M_OUT*4);
  float* att_nrm= (float*)alloc(M_OUT*4);
  unsigned* skey= (unsigned*)alloc(M_OUT*4);
  int* Ub       = (int*)alloc(256*4);
  int* offs     = (int*)alloc(257*4);
  int* us       = (int*)alloc(M_OUT*4);
  int* tails    = (int*)alloc((size_t)M_OUT*3*4);
  float* msg_agg= (float*)alloc((size_t)M_OUT*256*4);
  float* msg_sel= (float*)alloc((size_t)M_OUT*256*4);
  float* hrn_sel= (float*)alloc((size_t)M_OUT*256*4);
  (void)ws_size; (void)in_sizes; (void)n_in;

  // f32 output layout: [tail_nodes 16384*3 | hidden_node_new 16384*256 |
  //                     hidden_rel_out 16384*256 | att_agg_new 16384]
  float* out_f     = (float*)d_out;
  float* out_tail  = out_f;
  float* out_hn    = out_f + (size_t)M_OUT*3;
  float* out_hrel  = out_f + (size_t)M_OUT*3 + (size_t)M_OUT*256;
  float* out_aagg  = out_f + (size_t)M_OUT*3 + (size_t)2*M_OUT*256;

  // ---- zero output + accumulators + counters
  {
    int n0 = out_size;                        // f32 words
    zero_kernel<<<(n0+255)/256, 256, 0, stream>>>((unsigned*)d_out, n0);
    int n1 = M_OUT*256;
    zero_kernel<<<(n1+255)/256, 256, 0, stream>>>((unsigned*)msg_agg, n1);
    zero_kernel<<<(NPREV+255)/256, 256, 0, stream>>>((unsigned*)csr_cnt, NPREV);
    int n3 = M_OUT*3;
    zero_kernel<<<(n3+255)/256, 256, 0, stream>>>((unsigned*)tails, n3);
  }

  // ---- tiny precomputes for the att1 scalar decomposition
  matT_vec_kernel<<<1, 256, 0, stream>>>(w_msg, 512, 0,   att1w+256, wm1a);
  matT_vec_kernel<<<1, 256, 0, stream>>>(lets_w, 512, 0,  att1w+512, ve);
  matT_vec_kernel<<<1, 256, 0, stream>>>(lets_w, 512, 256,att1w+512, vts);
  c1_kernel<<<1, 64, 0, stream>>>(lets_b, att1w, att1b, consts);

  // ---- per-relation / per-entity / per-time tables
  tile_linear<1><<<(NREL+15)/16, 256, 0, stream>>>(rel_emd, 256, lrts_w, 256, 0, lrts_b, hr2, 256, NREL);
  tile_linear<1><<<(NREL+15)/16, 256, 0, stream>>>(hr2, 256, w_msg, 512, 256, b_msg, msg_r, 256, NREL);
  tile_linear<3><<<(NREL+15)/16, 256, 0, stream>>>(hr2, 256, w_ih, 256, 0, b_ih, gi, 768, NREL);
  tile_linear<1><<<(NTIME+15)/16, 256, 0, stream>>>(time_emd, 256, lets_w, 512, 256, (const float*)nullptr, time_t, 256, NTIME);
  tile_linear<1><<<(NENT+15)/16, 256, 0, stream>>>(ent_emd, 256, lets_w, 512, 0, lets_b, ent_t, 256, NENT);

  // ---- scalar tables
  rows_dot_kernel<<<(B_N*64+255)/256, 256, 0, stream>>>(query_emd, att1w, qdot, B_N);
  rows_dot_kernel<<<(NPREV*64+255)/256, 256, 0, stream>>>(hidden_node, wm1a, sn_m, NPREV);
  rows_dot_kernel<<<(NENT*64+255)/256, 256, 0, stream>>>(ent_emd, ve, se, NENT);
  rows_dot_kernel<<<(NTIME*64+255)/256, 256, 0, stream>>>(time_emd, vts, st, NTIME);
  rows_dot_kernel<<<(NREL*64+255)/256, 256, 0, stream>>>(msg_r, att1w+256, sr_m, NREL);

  // ---- CSR by node
  hist_kernel<<<(E_N+255)/256, 256, 0, stream>>>(facts, csr_cnt);
  csr_scan_kernel<<<1, 64, 0, stream>>>(csr_cnt, csr_off, csr_cur);
  scatter_kernel<<<(E_N+255)/256, 256, 0, stream>>>(facts, csr_cur, csr_edges);

  // ---- stage 1: attention per edge
  att_kernel<<<NPREV/16, 256, 0, stream>>>(hidden_rel, w_hh, b_hh, gi, att2w, att2b,
      facts, csr_off, csr_edges, qdot, sn_m, sr_m, se, st, consts, attention);

  // ---- stage 2: selection, unique, aggregation
  topk_kernel<<<B_N, 256, 0, stream>>>(facts, attention, att_agg, sel_edge, att_nrm, skey, Ub);
  offs_scan_kernel<<<1, 64, 0, stream>>>(Ub, offs);
  emit_kernel<<<B_N, 64, 0, stream>>>(skey, offs, us, tails, out_tail);
  sel_kernel<<<M_OUT/8, 256, 0, stream>>>(skey, sel_edge, att_nrm, facts,
      hidden_node, hidden_rel, w_msg, msg_r, gi, w_hh, b_hh, msg_sel, hrn_sel);
  segsum_kernel<<<B_N, 256, 0, stream>>>(skey, us, att_nrm, msg_sel, hrn_sel,
      msg_agg, out_hrel, out_aagg);
  final_kernel<<<M_OUT/16, 256, 0, stream>>>(msg_agg, tails, ent_t, time_t, w_h, b_h, out_hn);
}

// Round 3
// 2016.314 us; speedup vs baseline: 1.4284x; 1.4284x over previous
//
#include <hip/hip_runtime.h>
#include <hip/hip_bf16.h>

// Problem constants (fixed by setup_inputs)
#define E_N    100000
#define B_N    256
#define TOPK   64
#define NPREV  50000
#define NENT   20000
#define NTIME  2000
#define NREL   200
#define M_OUT  16384   // B_N * TOPK

static __device__ __forceinline__ float sigm(float x){ return 1.f/(1.f+expf(-x)); }

// ---------------------------------------------------------------- utilities
__global__ void zero_kernel(unsigned* __restrict__ p, int n){
  int i = blockIdx.x*256 + threadIdx.x;
  if (i < n) p[i] = 0u;
}

// dst[c*R + r] = src[r*C + c]   (R rows, C cols, C power of two)
__global__ void transpose_kernel(const float* __restrict__ src, float* __restrict__ dst,
                                 int R, int C){
  int i = blockIdx.x*256 + threadIdx.x;
  if (i < R*C){
    int r = i >> 8;          // C == 256
    int c = i & 255;
    dst[(size_t)c*R + r] = src[i];
  }
}

// out[k] = sum_d M[d*ldm + moff + k] * v[d],  k in [0,256), d in [0,256)
__global__ void matT_vec_kernel(const float* __restrict__ M, int ldm, int moff,
                                const float* __restrict__ v, float* __restrict__ out){
  int k = threadIdx.x;
  float acc = 0.f;
  for (int d = 0; d < 256; ++d) acc += M[(size_t)d*ldm + moff + k] * v[d];
  out[k] = acc;
}

// consts[0] = att_1_b[0] + dot(lin_e_ts_b, att_1_w[512:768])
__global__ void c1_kernel(const float* __restrict__ letsb, const float* __restrict__ att1w,
                          const float* __restrict__ att1b, float* __restrict__ consts){
  int lane = threadIdx.x;
  float p = 0.f;
  for (int d = lane; d < 256; d += 64) p += letsb[d]*att1w[512+d];
  for (int o = 32; o > 0; o >>= 1) p += __shfl_down(p, o);
  if (lane == 0) consts[0] = att1b[0] + p;
}

// out[i] = dot(A[i,:256], v)   (one wave per row)
__global__ void rows_dot_kernel(const float* __restrict__ A, const float* __restrict__ v,
                                float* __restrict__ out, int nrows){
  int gid = blockIdx.x*blockDim.x + threadIdx.x;
  int wid = gid >> 6, lane = gid & 63;
  if (wid >= nrows) return;
  const float* row = A + (size_t)wid*256;
  float p = 0.f;
  for (int k = lane; k < 256; k += 64) p += row[k]*v[k];
  for (int o = 32; o > 0; o >>= 1) p += __shfl_down(p, o);
  if (lane == 0) out[wid] = p;
}

// out[row, d + 256*q] = bias[d+256q] + sum_k A[row,k]*Bw[(d+256q)*ldb + boff + k]
// 16 rows per block, thread = output dim d, K = 256.
template<int ND>
__global__ __launch_bounds__(256) void tile_linear(
    const float* __restrict__ A, int lda,
    const float* __restrict__ Bw, int ldb, int boff,
    const float* __restrict__ bias,
    float* __restrict__ out, int ldo, int rows){
  __shared__ float a_s[16][260];
  int tile0 = blockIdx.x*16;
  for (int idx = threadIdx.x; idx < 16*256; idx += 256){
    int i = idx >> 8, k = idx & 255;
    int row = tile0 + i;
    a_s[i][k] = (row < rows) ? A[(size_t)row*lda + k] : 0.f;
  }
  __syncthreads();
  int d = threadIdx.x;
  const float* brow[ND];
  #pragma unroll
  for (int q = 0; q < ND; ++q) brow[q] = Bw + (size_t)(d + 256*q)*ldb + boff;
  float acc[ND][16];
  #pragma unroll
  for (int q = 0; q < ND; ++q){
    float bv = bias ? bias[d + 256*q] : 0.f;
    #pragma unroll
    for (int i = 0; i < 16; ++i) acc[q][i] = bv;
  }
  for (int k = 0; k < 256; k += 4){
    float4 w[ND];
    #pragma unroll
    for (int q = 0; q < ND; ++q) w[q] = *(const float4*)(brow[q] + k);
    #pragma unroll
    for (int i = 0; i < 16; ++i){
      float4 a = *(const float4*)&a_s[i][k];
      #pragma unroll
      for (int q = 0; q < ND; ++q)
        acc[q][i] += w[q].x*a.x + w[q].y*a.y + w[q].z*a.z + w[q].w*a.w;
    }
  }
  #pragma unroll
  for (int i = 0; i < 16; ++i){
    int row = tile0 + i;
    if (row < rows){
      #pragma unroll
      for (int q = 0; q < ND; ++q) out[(size_t)row*ldo + d + 256*q] = acc[q][i];
    }
  }
}

// ---------------------------------------------------------------- CSR by node
__global__ void hist_kernel(const int* __restrict__ facts, int* __restrict__ cnt){
  int e = blockIdx.x*256 + threadIdx.x;
  if (e < E_N) atomicAdd(&cnt[facts[e*6+1]], 1);
}

__global__ void csr_scan_kernel(const int* __restrict__ cnt, int* __restrict__ off,
                                int* __restrict__ cur){
  int lane = threadIdx.x;   // 64 threads, 1 block
  int run = 0;
  for (int base = 0; base < NPREV; base += 64){
    int idx = base + lane;
    int orig = (idx < NPREV) ? cnt[idx] : 0;
    int v = orig;
    for (int o = 1; o < 64; o <<= 1){ int t = __shfl_up(v, o); if (lane >= o) v += t; }
    if (idx < NPREV){ int ex = run + v - orig; off[idx] = ex; cur[idx] = ex; }
    run += __shfl(v, 63);
  }
  if (lane == 0) off[NPREV] = E_N;
}

__global__ void scatter_kernel(const int* __restrict__ facts, int* __restrict__ cur,
                               int* __restrict__ edges){
  int e = blockIdx.x*256 + threadIdx.x;
  if (e < E_N){
    int n = facts[e*6+1];
    int p = atomicAdd(&cur[n], 1);
    edges[p] = e;
  }
}

// ---------------------------------------------------------------- stage 1: attention per edge
// Phase 1: gh = hidden_rel[tile] @ w_hh^T + b_hh  via k-major transposed weights
//          (coalesced w loads, wave-uniform broadcast A loads) -> LDS.
// Phase 2: barrier-free wave-per-edge GRU + att2 dot + att1 from scalar tables.
__global__ __launch_bounds__(256) void att_kernel(
    const float* __restrict__ hidden_rel,
    const float* __restrict__ wTh,    // [256][768] k-major transpose of w_hh
    const float* __restrict__ b_hh,
    const float* __restrict__ gi,     // [NREL][768] (includes b_ih)
    const float* __restrict__ att2w, const float* __restrict__ att2b,
    const int* __restrict__ facts,
    const int* __restrict__ csr_off, const int* __restrict__ csr_edges,
    const float* __restrict__ qdot, const float* __restrict__ sn_m,
    const float* __restrict__ sr_m, const float* __restrict__ se,
    const float* __restrict__ st,   const float* __restrict__ consts,
    float* __restrict__ attention){
  __shared__ float gh_s[16][776];   // 768 + 8 pad = 49664 B
  int tile0 = blockIdx.x*16;
  int t = threadIdx.x;

  // ---- phase 1: thread t computes dims {t, t+256, t+512} for all 16 nodes
  float acc[3][16];
  #pragma unroll
  for (int q = 0; q < 3; ++q)
    #pragma unroll
    for (int p = 0; p < 16; ++p) acc[q][p] = 0.f;

  for (int k = 0; k < 256; k += 4){
    float w[4][3];
    #pragma unroll
    for (int kk = 0; kk < 4; ++kk)
      #pragma unroll
      for (int q = 0; q < 3; ++q)
        w[kk][q] = wTh[(size_t)(k+kk)*768 + t + 256*q];
    #pragma unroll
    for (int p = 0; p < 16; ++p){
      float4 a = *(const float4*)&hidden_rel[(size_t)(tile0+p)*256 + k];  // uniform -> broadcast
      #pragma unroll
      for (int q = 0; q < 3; ++q)
        acc[q][p] += w[0][q]*a.x + w[1][q]*a.y + w[2][q]*a.z + w[3][q]*a.w;
    }
  }
  #pragma unroll
  for (int q = 0; q < 3; ++q){
    float bv = b_hh[t + 256*q];
    #pragma unroll
    for (int p = 0; p < 16; ++p)
      gh_s[p][t + 256*q] = acc[q][p] + bv;
  }
  __syncthreads();

  // ---- phase 2: wave per edge, lane l covers dims 4l..4l+3
  int wv = t >> 6, l = t & 63;
  int o0 = csr_off[tile0], o1 = csr_off[tile0 + 16];
  int d0 = 4*l;
  float4 a2 = *(const float4*)&att2w[d0];
  float c1 = consts[0];
  float a2b = att2b[0];
  for (int idx = o0 + wv; idx < o1; idx += 4){
    int e  = csr_edges[idx];
    int b  = facts[e*6+0], n = facts[e*6+1], r = facts[e*6+3];
    int t_ = facts[e*6+4], ts_ = facts[e*6+5];
    int nl = n - tile0;
    float4 ghr = *(const float4*)&gh_s[nl][d0];
    float4 ghz = *(const float4*)&gh_s[nl][256+d0];
    float4 ghn = *(const float4*)&gh_s[nl][512+d0];
    const float* girow = gi + (size_t)r*768;
    float4 gir = *(const float4*)&girow[d0];
    float4 giz = *(const float4*)&girow[256+d0];
    float4 gin = *(const float4*)&girow[512+d0];
    float4 hp  = *(const float4*)&hidden_rel[(size_t)n*256 + d0];
    float partial;
    {
      float rg = sigm(gir.x + ghr.x), zg = sigm(giz.x + ghz.x);
      float ng = tanhf(gin.x + rg*ghn.x);
      partial = a2.x * ((1.f - zg)*ng + zg*hp.x);
    }{
      float rg = sigm(gir.y + ghr.y), zg = sigm(giz.y + ghz.y);
      float ng = tanhf(gin.y + rg*ghn.y);
      partial += a2.y * ((1.f - zg)*ng + zg*hp.y);
    }{
      float rg = sigm(gir.z + ghr.z), zg = sigm(giz.z + ghz.z);
      float ng = tanhf(gin.z + rg*ghn.z);
      partial += a2.z * ((1.f - zg)*ng + zg*hp.z);
    }{
      float rg = sigm(gir.w + ghr.w), zg = sigm(giz.w + ghz.w);
      float ng = tanhf(gin.w + rg*ghn.w);
      partial += a2.w * ((1.f - zg)*ng + zg*hp.w);
    }
    #pragma unroll
    for (int o = 32; o > 0; o >>= 1) partial += __shfl_xor(partial, o);
    if (l == 0){
      float att2 = sigm(partial + a2b);
      float x1 = qdot[b] + sn_m[n] + sr_m[r] + se[t_] + st[ts_] + c1;
      attention[e] = 0.5f*(sigm(x1) + att2);
    }
  }
}

// ---------------------------------------------------------------- stage 2: per-batch top-64
__global__ __launch_bounds__(256) void topk_kernel(
    const int* __restrict__ facts, const float* __restrict__ attention,
    const float* __restrict__ att_agg,
    int* __restrict__ sel_edge, float* __restrict__ att_norm,
    unsigned* __restrict__ skey, int* __restrict__ Ub){
  __shared__ float sa[512];
  __shared__ int   si[512];
  __shared__ unsigned sk[64];
  __shared__ int cnt;
  int b = blockIdx.x, tid = threadIdx.x;
  sa[tid] = -1.f; sa[tid+256] = -1.f;
  si[tid] = 0x7fffffff; si[tid+256] = 0x7fffffff;
  if (tid == 0) cnt = 0;
  __syncthreads();
  for (int e = tid; e < E_N; e += 256){
    if (facts[e*6] == b){
      int p = atomicAdd(&cnt, 1);
      if (p < 512){ sa[p] = attention[e]; si[p] = e; }
    }
  }
  __syncthreads();
  // bitonic sort: attention desc, edge index asc (matches stable lexsort)
  for (int k = 2; k <= 512; k <<= 1){
    for (int j = k >> 1; j > 0; j >>= 1){
      for (int i0 = tid; i0 < 512; i0 += 256){
        int l = i0 ^ j;
        if (l > i0){
          float ai = sa[i0], al = sa[l];
          int   ii = si[i0], il = si[l];
          bool lFirst = (al > ai) || (al == ai && il < ii);
          bool up = ((i0 & k) == 0);
          if (up ? lFirst : !lFirst){
            sa[i0] = al; sa[l] = ai; si[i0] = il; si[l] = ii;
          }
        }
      }
      __syncthreads();
    }
  }
  // selected 64: raw att * att_agg[n], normalize by per-batch sum
  if (tid < 64){
    int e = si[tid];
    bool valid = (e != 0x7fffffff);
    if (!valid) e = 0;
    int n = facts[e*6+1];
    float a = valid ? sa[tid]*att_agg[n] : 0.f;
    float den = a;
    for (int o = 32; o > 0; o >>= 1) den += __shfl_down(den, o);
    den = __shfl(den, 0);
    float norm = (den != 0.f) ? a/den : 0.f;
    sel_edge[b*64 + tid] = e;
    att_norm[b*64 + tid] = norm;
    int t_ = facts[e*6+4], ts_ = facts[e*6+5];
    unsigned key = (((unsigned)t_) << 11) | (unsigned)ts_;
    sk[tid] = (key << 6) | (unsigned)tid;
  }
  __syncthreads();
  // sort 64 keys ascending ((t,ts) then slot) -- matches jnp.unique row sort per batch
  for (int k = 2; k <= 64; k <<= 1){
    for (int j = k >> 1; j > 0; j >>= 1){
      unsigned nv = 0; bool act = tid < 64;
      if (act){
        unsigned mine = sk[tid], other = sk[tid ^ j];
        bool up = ((tid & k) == 0);
        bool keepmin = (up == ((tid & j) == 0));
        nv = keepmin ? (mine < other ? mine : other) : (mine > other ? mine : other);
      }
      __syncthreads();
      if (act) sk[tid] = nv;
      __syncthreads();
    }
  }
  if (tid < 64){
    unsigned kk = sk[tid];
    skey[b*64 + tid] = kk;
    bool head = (tid == 0) || ((kk >> 6) != (sk[tid-1] >> 6));
    unsigned long long bal = __ballot(head);
    if (tid == 0) Ub[b] = __popcll(bal);
  }
}

__global__ void offs_scan_kernel(const int* __restrict__ Ub, int* __restrict__ offs){
  int lane = threadIdx.x;  // 64 threads, 1 block
  int run = 0;
  for (int base = 0; base < 256; base += 64){
    int orig = Ub[base + lane];
    int v = orig;
    for (int o = 1; o < 64; o <<= 1){ int t = __shfl_up(v, o); if (lane >= o) v += t; }
    offs[base + lane] = run + v - orig;
    run += __shfl(v, 63);
  }
  if (lane == 0) offs[256] = run;
}

__global__ void emit_kernel(const unsigned* __restrict__ skey, const int* __restrict__ offs,
                            int* __restrict__ us, int* __restrict__ tails,
                            float* __restrict__ out_tail){
  int b = blockIdx.x, tid = threadIdx.x;  // block of 64
  unsigned kk = skey[b*64 + tid];
  bool head = (tid == 0) || ((kk >> 6) != (skey[b*64 + tid - 1] >> 6));
  unsigned long long bal = __ballot(head);
  unsigned long long mask_le = (tid == 63) ? ~0ull : ((1ull << (tid+1)) - 1ull);
  int ulocal = __popcll(bal & mask_le) - 1;
  int u = offs[b] + ulocal;
  us[b*64 + tid] = u;
  if (head){
    unsigned key = kk >> 6;
    int t_ = (int)(key >> 11), ts_ = (int)(key & 2047u);
    tails[u*3+0] = b; tails[u*3+1] = t_; tails[u*3+2] = ts_;
    out_tail[u*3+0] = (float)b;
    out_tail[u*3+1] = (float)t_;
    out_tail[u*3+2] = (float)ts_;
  }
}

// ---------------------------------------------------------------- selected-edge vectors
// For the 16384 selected edges (in per-batch sorted order), recompute
// message and hidden_rel_new, premultiplied by normalized attention.
__global__ __launch_bounds__(256) void sel_kernel(
    const unsigned* __restrict__ skey, const int* __restrict__ sel_edge,
    const float* __restrict__ att_norm, const int* __restrict__ facts,
    const float* __restrict__ hidden_node, const float* __restrict__ hidden_rel,
    const float* __restrict__ w_msg, const float* __restrict__ msg_r,
    const float* __restrict__ gi, const float* __restrict__ w_hh,
    const float* __restrict__ b_hh,
    float* __restrict__ msg_sel, float* __restrict__ hrn_sel){
  __shared__ float hn_s[8][260];
  __shared__ float hr_s[8][260];
  __shared__ int n_s[8], r_s[8];
  __shared__ float av_s[8];
  int base = blockIdx.x*8;
  int d = threadIdx.x;
  if (d < 8){
    int gs = base + d;
    int b = gs >> 6, i = gs & 63;
    int j = (int)(skey[(size_t)b*64 + i] & 63u);
    int s = b*64 + j;
    int e = sel_edge[s];
    n_s[d] = facts[e*6+1];
    r_s[d] = facts[e*6+3];
    av_s[d] = att_norm[s];
  }
  __syncthreads();
  for (int idx = d; idx < 8*256; idx += 256){
    int ii = idx >> 8, k = idx & 255;
    int n = n_s[ii];
    hn_s[ii][k] = hidden_node[(size_t)n*256 + k];
    hr_s[ii][k] = hidden_rel[(size_t)n*256 + k];
  }
  __syncthreads();
  const float* wm = w_msg + (size_t)d*512;         // first 256 cols of W_message row d
  const float* wr = w_hh + (size_t)d*256;
  const float* wz = w_hh + (size_t)(256+d)*256;
  const float* wn = w_hh + (size_t)(512+d)*256;
  float sm[8] = {0,0,0,0,0,0,0,0};
  float sr[8] = {0,0,0,0,0,0,0,0};
  float sz[8] = {0,0,0,0,0,0,0,0};
  float sn2[8] = {0,0,0,0,0,0,0,0};
  for (int k = 0; k < 256; k += 4){
    float4 w0 = *(const float4*)(wm + k);
    float4 w1 = *(const float4*)(wr + k);
    float4 w2 = *(const float4*)(wz + k);
    float4 w3 = *(const float4*)(wn + k);
    #pragma unroll
    for (int ii = 0; ii < 8; ++ii){
      float4 a = *(const float4*)&hn_s[ii][k];
      float4 h = *(const float4*)&hr_s[ii][k];
      sm[ii]  += w0.x*a.x + w0.y*a.y + w0.z*a.z + w0.w*a.w;
      sr[ii]  += w1.x*h.x + w1.y*h.y + w1.z*h.z + w1.w*h.w;
      sz[ii]  += w2.x*h.x + w2.y*h.y + w2.z*h.z + w2.w*h.w;
      sn2[ii] += w3.x*h.x + w3.y*h.y + w3.z*h.z + w3.w*h.w;
    }
  }
  float bhr = b_hh[d], bhz = b_hh[256+d], bhn = b_hh[512+d];
  #pragma unroll
  for (int ii = 0; ii < 8; ++ii){
    int r = r_s[ii]; float a = av_s[ii];
    const float* girow = gi + (size_t)r*768;
    float msgv = sm[ii] + msg_r[(size_t)r*256 + d];
    float rg = sigm(girow[d]      + sr[ii] + bhr);
    float zg = sigm(girow[256+d]  + sz[ii] + bhz);
    float ng = tanhf(girow[512+d] + rg*(sn2[ii] + bhn));
    float hrn = (1.f - zg)*ng + zg*hr_s[ii][d];
    size_t o = (size_t)(base + ii)*256 + d;
    msg_sel[o] = a*msgv;
    hrn_sel[o] = a*hrn;
  }
}

// ---------------------------------------------------------------- deterministic segment sums
__global__ __launch_bounds__(256) void segsum_kernel(
    const unsigned* __restrict__ skey, const int* __restrict__ us,
    const float* __restrict__ att_norm,
    const float* __restrict__ msg_sel, const float* __restrict__ hrn_sel,
    float* __restrict__ msg_agg, float* __restrict__ out_hrel,
    float* __restrict__ out_aagg){
  int b = blockIdx.x, d = threadIdx.x;
  float accm = 0.f, acch = 0.f, acca = 0.f;
  int ucur = -1;
  for (int i = 0; i < 64; ++i){
    int u = us[b*64 + i];
    if (u != ucur){
      if (ucur >= 0){
        msg_agg[(size_t)ucur*256 + d] = accm;
        out_hrel[(size_t)ucur*256 + d] = acch;
        if (d == 0) out_aagg[ucur] = acca;
      }
      ucur = u; accm = 0.f; acch = 0.f; acca = 0.f;
    }
    size_t o = (size_t)(b*64 + i)*256 + d;
    accm += msg_sel[o];
    acch += hrn_sel[o];
    int j = (int)(skey[b*64 + i] & 63u);
    acca += att_norm[b*64 + j];
  }
  if (ucur >= 0){
    msg_agg[(size_t)ucur*256 + d] = accm;
    out_hrel[(size_t)ucur*256 + d] = acch;
    if (d == 0) out_aagg[ucur] = acca;
  }
}

// ---------------------------------------------------------------- final linear
// hidden_node_new[u] = [msg_agg[u] | ent_t[t_u]+time_t[ts_u]] @ W_h^T + b_h
__global__ __launch_bounds__(256) void final_kernel(
    const float* __restrict__ msg_agg, const int* __restrict__ tails,
    const float* __restrict__ ent_t, const float* __restrict__ time_t,
    const float* __restrict__ w_h, const float* __restrict__ b_h,
    float* __restrict__ out_hn){
  __shared__ float x_s[16][520];
  int tile0 = blockIdx.x*16;
  for (int idx = threadIdx.x; idx < 16*512; idx += 256){
    int i = idx >> 9, k = idx & 511;
    int u = tile0 + i;
    float v;
    if (k < 256) v = msg_agg[(size_t)u*256 + k];
    else {
      int kk = k - 256;
      v = ent_t[(size_t)tails[u*3+1]*256 + kk] + time_t[(size_t)tails[u*3+2]*256 + kk];
    }
    x_s[i][k] = v;
  }
  __syncthreads();
  int d = threadIdx.x;
  const float* wrow = w_h + (size_t)d*512;
  float bv = b_h[d];
  float acc[16];
  #pragma unroll
  for (int i = 0; i < 16; ++i) acc[i] = bv;
  for (int k = 0; k < 512; k += 4){
    float4 w = *(const float4*)(wrow + k);
    #pragma unroll
    for (int i = 0; i < 16; ++i){
      float4 a = *(const float4*)&x_s[i][k];
      acc[i] += w.x*a.x + w.y*a.y + w.z*a.z + w.w*a.w;
    }
  }
  #pragma unroll
  for (int i = 0; i < 16; ++i)
    out_hn[(size_t)(tile0+i)*256 + d] = acc[i];
}

// ================================================================ launcher
extern "C" void kernel_launch(void* const* d_in, const int* in_sizes, int n_in,
                              void* d_out, int out_size, void* d_ws, size_t ws_size,
                              hipStream_t stream){
  const float* query_emd   = (const float*)d_in[1];
  const int*   facts       = (const int*)  d_in[2];
  const float* ent_emd     = (const float*)d_in[3];
  const float* rel_emd     = (const float*)d_in[4];
  const float* hidden_node = (const float*)d_in[5];
  const float* hidden_rel  = (const float*)d_in[6];
  const float* att_agg     = (const float*)d_in[8];
  const float* time_emd    = (const float*)d_in[9];
  const float* w_msg       = (const float*)d_in[11];
  const float* b_msg       = (const float*)d_in[12];
  const float* att1w       = (const float*)d_in[13];
  const float* att1b       = (const float*)d_in[14];
  const float* att2w       = (const float*)d_in[15];
  const float* att2b       = (const float*)d_in[16];
  const float* w_h         = (const float*)d_in[17];
  const float* b_h         = (const float*)d_in[18];
  const float* lets_w      = (const float*)d_in[19];
  const float* lets_b      = (const float*)d_in[20];
  const float* lrts_w      = (const float*)d_in[21];
  const float* lrts_b      = (const float*)d_in[22];
  const float* w_ih        = (const float*)d_in[25];
  const float* w_hh        = (const float*)d_in[26];
  const float* b_ih        = (const float*)d_in[27];
  const float* b_hh        = (const float*)d_in[28];

  // ---- workspace carve (total ~77 MB)
  char* p = (char*)d_ws;
  auto alloc = [&](size_t bytes) -> void* {
    void* r = (void*)p; p += (bytes + 255) & ~(size_t)255; return r;
  };
  float* attention = (float*)alloc(E_N*4);
  float* qdot   = (float*)alloc(256*4);
  float* sn_m   = (float*)alloc(NPREV*4);
  float* se     = (float*)alloc(NENT*4);
  float* st     = (float*)alloc(NTIME*4);
  float* sr_m   = (float*)alloc(NREL*4);
  float* wm1a   = (float*)alloc(256*4);
  float* ve     = (float*)alloc(256*4);
  float* vts    = (float*)alloc(256*4);
  float* consts = (float*)alloc(8*4);
  float* hr2    = (float*)alloc((size_t)NREL*256*4);
  float* msg_r  = (float*)alloc((size_t)NREL*256*4);
  float* gi     = (float*)alloc((size_t)NREL*768*4);
  float* time_t = (float*)alloc((size_t)NTIME*256*4);
  float* ent_t  = (float*)alloc((size_t)NENT*256*4);
  float* wTh    = (float*)alloc((size_t)256*768*4);   // k-major transpose of w_hh
  int* csr_cnt  = (int*)alloc(NPREV*4);
  int* csr_off  = (int*)alloc((NPREV+1)*4);
  int* csr_cur  = (int*)alloc(NPREV*4);
  int* csr_edges= (int*)alloc(E_N*4);
  int* sel_edge = (int*)alloc(M_OUT*4);
  float* att_nrm= (float*)alloc(M_OUT*4);
  unsigned* skey= (unsigned*)alloc(M_OUT*4);
  int* Ub       = (int*)alloc(256*4);
  int* offs     = (int*)alloc(257*4);
  int* us       = (int*)alloc(M_OUT*4);
  int* tails    = (int*)alloc((size_t)M_OUT*3*4);
  float* msg_agg= (float*)alloc((size_t)M_OUT*256*4);
  float* msg_sel= (float*)alloc((size_t)M_OUT*256*4);
  float* hrn_sel= (float*)alloc((size_t)M_OUT*256*4);
  (void)ws_size; (void)in_sizes; (void)n_in;

  // f32 output layout: [tail_nodes 16384*3 | hidden_node_new 16384*256 |
  //                     hidden_rel_out 16384*256 | att_agg_new 16384]
  float* out_f     = (float*)d_out;
  float* out_tail  = out_f;
  float* out_hn    = out_f + (size_t)M_OUT*3;
  float* out_hrel  = out_f + (size_t)M_OUT*3 + (size_t)M_OUT*256;
  float* out_aagg  = out_f + (size_t)M_OUT*3 + (size_t)2*M_OUT*256;

  // ---- zero output + accumulators + counters
  {
    int n0 = out_size;                        // f32 words
    zero_kernel<<<(n0+255)/256, 256, 0, stream>>>((unsigned*)d_out, n0);
    int n1 = M_OUT*256;
    zero_kernel<<<(n1+255)/256, 256, 0, stream>>>((unsigned*)msg_agg, n1);
    zero_kernel<<<(NPREV+255)/256, 256, 0, stream>>>((unsigned*)csr_cnt, NPREV);
    int n3 = M_OUT*3;
    zero_kernel<<<(n3+255)/256, 256, 0, stream>>>((unsigned*)tails, n3);
  }

  // ---- tiny precomputes for the att1 scalar decomposition
  matT_vec_kernel<<<1, 256, 0, stream>>>(w_msg, 512, 0,   att1w+256, wm1a);
  matT_vec_kernel<<<1, 256, 0, stream>>>(lets_w, 512, 0,  att1w+512, ve);
  matT_vec_kernel<<<1, 256, 0, stream>>>(lets_w, 512, 256,att1w+512, vts);
  c1_kernel<<<1, 64, 0, stream>>>(lets_b, att1w, att1b, consts);

  // ---- weight transpose (w_hh: [768][256] -> wTh [256][768])
  transpose_kernel<<<(768*256+255)/256, 256, 0, stream>>>(w_hh, wTh, 768, 256);

  // ---- per-relation / per-entity / per-time tables
  tile_linear<1><<<(NREL+15)/16, 256, 0, stream>>>(rel_emd, 256, lrts_w, 256, 0, lrts_b, hr2, 256, NREL);
  tile_linear<1><<<(NREL+15)/16, 256, 0, stream>>>(hr2, 256, w_msg, 512, 256, b_msg, msg_r, 256, NREL);
  tile_linear<3><<<(NREL+15)/16, 256, 0, stream>>>(hr2, 256, w_ih, 256, 0, b_ih, gi, 768, NREL);
  tile_linear<1><<<(NTIME+15)/16, 256, 0, stream>>>(time_emd, 256, lets_w, 512, 256, (const float*)nullptr, time_t, 256, NTIME);
  tile_linear<1><<<(NENT+15)/16, 256, 0, stream>>>(ent_emd, 256, lets_w, 512, 0, lets_b, ent_t, 256, NENT);

  // ---- scalar tables
  rows_dot_kernel<<<(B_N*64+255)/256, 256, 0, stream>>>(query_emd, att1w, qdot, B_N);
  rows_dot_kernel<<<(NPREV*64+255)/256, 256, 0, stream>>>(hidden_node, wm1a, sn_m, NPREV);
  rows_dot_kernel<<<(NENT*64+255)/256, 256, 0, stream>>>(ent_emd, ve, se, NENT);
  rows_dot_kernel<<<(NTIME*64+255)/256, 256, 0, stream>>>(time_emd, vts, st, NTIME);
  rows_dot_kernel<<<(NREL*64+255)/256, 256, 0, stream>>>(msg_r, att1w+256, sr_m, NREL);

  // ---- CSR by node
  hist_kernel<<<(E_N+255)/256, 256, 0, stream>>>(facts, csr_cnt);
  csr_scan_kernel<<<1, 64, 0, stream>>>(csr_cnt, csr_off, csr_cur);
  scatter_kernel<<<(E_N+255)/256, 256, 0, stream>>>(facts, csr_cur, csr_edges);

  // ---- stage 1: attention per edge
  att_kernel<<<NPREV/16, 256, 0, stream>>>(hidden_rel, wTh, b_hh, gi, att2w, att2b,
      facts, csr_off, csr_edges, qdot, sn_m, sr_m, se, st, consts, attention);

  // ---- stage 2: selection, unique, aggregation
  topk_kernel<<<B_N, 256, 0, stream>>>(facts, attention, att_agg, sel_edge, att_nrm, skey, Ub);
  offs_scan_kernel<<<1, 64, 0, stream>>>(Ub, offs);
  emit_kernel<<<B_N, 64, 0, stream>>>(skey, offs, us, tails, out_tail);
  sel_kernel<<<M_OUT/8, 256, 0, stream>>>(skey, sel_edge, att_nrm, facts,
      hidden_node, hidden_rel, w_msg, msg_r, gi, w_hh, b_hh, msg_sel, hrn_sel);
  segsum_kernel<<<B_N, 256, 0, stream>>>(skey, us, att_nrm, msg_sel, hrn_sel,
      msg_agg, out_hrel, out_aagg);
  final_kernel<<<M_OUT/16, 256, 0, stream>>>(msg_agg, tails, ent_t, time_t, w_h, b_h, out_hn);
}

// Round 4
// 1189.748 us; speedup vs baseline: 2.4208x; 1.6947x over previous
//
#include <hip/hip_runtime.h>
#include <hip/hip_bf16.h>

// Problem constants (fixed by setup_inputs)
#define E_N    100000
#define B_N    256
#define TOPK   64
#define NPREV  50000
#define NENT   20000
#define NTIME  2000
#define NREL   200
#define M_OUT  16384   // B_N * TOPK
#define NTILE  3125    // NPREV/16

static __device__ __forceinline__ float sigm(float x){ return 1.f/(1.f+expf(-x)); }

// ---------------------------------------------------------------- utilities
__global__ void zero_kernel(unsigned* __restrict__ p, int n){
  int i = blockIdx.x*256 + threadIdx.x;
  if (i < n) p[i] = 0u;
}

// Pack weights float4 k-major: wP[kblk][mat][t][kk]
// mat0 = w_msg[t][k] (first 256 cols), mat1..3 = w_hh[(m-1)*256 + t][k]
__global__ void pack_w_kernel(const float* __restrict__ w_msg,
                              const float* __restrict__ w_hh,
                              float4* __restrict__ wP){
  int i = blockIdx.x*256 + threadIdx.x;   // (kblk*4 + mat)*256 + t, 65536 total
  if (i < 65536){
    int t = i & 255;
    int mat = (i >> 8) & 3;
    int kblk = i >> 10;
    float4 v;
    if (mat == 0) v = *(const float4*)&w_msg[(size_t)t*512 + kblk*4];
    else          v = *(const float4*)&w_hh[(size_t)((mat-1)*256 + t)*256 + kblk*4];
    wP[i] = v;
  }
}

// 4 blocks: 0 -> wm1a, 1 -> ve, 2 -> vts, 3 -> consts[0]
__global__ void matvec_fused(const float* __restrict__ w_msg,
                             const float* __restrict__ lets_w,
                             const float* __restrict__ lets_b,
                             const float* __restrict__ att1w,
                             const float* __restrict__ att1b,
                             float* __restrict__ wm1a, float* __restrict__ ve,
                             float* __restrict__ vts, float* __restrict__ consts){
  int blk = blockIdx.x, t = threadIdx.x;
  if (blk == 3){
    if (t < 64){
      float p = 0.f;
      for (int d = t; d < 256; d += 64) p += lets_b[d]*att1w[512+d];
      for (int o = 32; o > 0; o >>= 1) p += __shfl_down(p, o);
      if (t == 0) consts[0] = att1b[0] + p;
    }
    return;
  }
  const float* M; int moff; const float* v; float* out;
  if (blk == 0){ M = w_msg;  moff = 0;   v = att1w+256; out = wm1a; }
  else if (blk == 1){ M = lets_w; moff = 0;   v = att1w+512; out = ve; }
  else { M = lets_w; moff = 256; v = att1w+512; out = vts; }
  float acc = 0.f;
  for (int d = 0; d < 256; ++d) acc += M[(size_t)d*512 + moff + t] * v[d];
  out[t] = acc;
}

// fused scalar tables: out[i] = dot(A[i,:256], v) per segment
__global__ void rows_dot_multi(
    const float* __restrict__ A0, const float* __restrict__ v0, float* __restrict__ o0, int n0,
    const float* __restrict__ A1, const float* __restrict__ v1, float* __restrict__ o1_, int n1,
    const float* __restrict__ A2, const float* __restrict__ v2, float* __restrict__ o2, int n2,
    const float* __restrict__ A3, const float* __restrict__ v3, float* __restrict__ o3, int n3,
    const float* __restrict__ A4, const float* __restrict__ v4, float* __restrict__ o4, int n4){
  int gid = blockIdx.x*256 + threadIdx.x;
  int wid = gid >> 6, lane = gid & 63;
  const float* A; const float* v; float* o; int r;
  if (wid < n0){ A=A0; v=v0; o=o0; r=wid; }
  else if ((wid -= n0) < n1){ A=A1; v=v1; o=o1_; r=wid; }
  else if ((wid -= n1) < n2){ A=A2; v=v2; o=o2; r=wid; }
  else if ((wid -= n2) < n3){ A=A3; v=v3; o=o3; r=wid; }
  else if ((wid -= n3) < n4){ A=A4; v=v4; o=o4; r=wid; }
  else return;
  const float* row = A + (size_t)r*256;
  float p = 0.f;
  for (int k = lane; k < 256; k += 64) p += row[k]*v[k];
  for (int off = 32; off > 0; off >>= 1) p += __shfl_down(p, off);
  if (lane == 0) o[r] = p;
}

// out[row, d + 256*q] = bias[d+256q] + sum_k A[row,k]*Bw[(d+256q)*ldb + boff + k]
template<int ND>
__global__ __launch_bounds__(256) void tile_linear(
    const float* __restrict__ A, int lda,
    const float* __restrict__ Bw, int ldb, int boff,
    const float* __restrict__ bias,
    float* __restrict__ out, int ldo, int rows){
  __shared__ float a_s[16][260];
  int tile0 = blockIdx.x*16;
  for (int idx = threadIdx.x; idx < 16*256; idx += 256){
    int i = idx >> 8, k = idx & 255;
    int row = tile0 + i;
    a_s[i][k] = (row < rows) ? A[(size_t)row*lda + k] : 0.f;
  }
  __syncthreads();
  int d = threadIdx.x;
  const float* brow[ND];
  #pragma unroll
  for (int q = 0; q < ND; ++q) brow[q] = Bw + (size_t)(d + 256*q)*ldb + boff;
  float acc[ND][16];
  #pragma unroll
  for (int q = 0; q < ND; ++q){
    float bv = bias ? bias[d + 256*q] : 0.f;
    #pragma unroll
    for (int i = 0; i < 16; ++i) acc[q][i] = bv;
  }
  for (int k = 0; k < 256; k += 4){
    float4 w[ND];
    #pragma unroll
    for (int q = 0; q < ND; ++q) w[q] = *(const float4*)(brow[q] + k);
    #pragma unroll
    for (int i = 0; i < 16; ++i){
      float4 a = *(const float4*)&a_s[i][k];
      #pragma unroll
      for (int q = 0; q < ND; ++q)
        acc[q][i] += w[q].x*a.x + w[q].y*a.y + w[q].z*a.z + w[q].w*a.w;
    }
  }
  #pragma unroll
  for (int i = 0; i < 16; ++i){
    int row = tile0 + i;
    if (row < rows){
      #pragma unroll
      for (int q = 0; q < ND; ++q) out[(size_t)row*ldo + d + 256*q] = acc[q][i];
    }
  }
}

// ---------------------------------------------------------------- bins by tile-of-16
__global__ void hist_kernel(const int* __restrict__ facts, int* __restrict__ cnt){
  int e = blockIdx.x*256 + threadIdx.x;
  if (e < E_N) atomicAdd(&cnt[facts[e*6+1] >> 4], 1);
}

__global__ void bin_scan_kernel(const int* __restrict__ cnt, int* __restrict__ off,
                                int* __restrict__ cur){
  int lane = threadIdx.x;   // 64 threads, 1 block
  int run = 0;
  for (int base = 0; base < 3136; base += 64){
    int idx = base + lane;
    int orig = (idx < NTILE) ? cnt[idx] : 0;
    int v = orig;
    for (int o = 1; o < 64; o <<= 1){ int t = __shfl_up(v, o); if (lane >= o) v += t; }
    if (idx < NTILE){ int ex = run + v - orig; off[idx] = ex; cur[idx] = ex; }
    run += __shfl(v, 63);
  }
  if (lane == 0) off[NTILE] = E_N;
}

__global__ void scatter_kernel(const int* __restrict__ facts, int* __restrict__ cur,
                               int* __restrict__ edges){
  int e = blockIdx.x*256 + threadIdx.x;
  if (e < E_N){
    int p = atomicAdd(&cur[facts[e*6+1] >> 4], 1);
    edges[p] = e;
  }
}

// ---------------------------------------------------------------- stage 1: attention per edge
// Phase 1: gh = hidden_rel[tile] @ w_hh^T + b_hh via float4 k-major packed weights
//          (3 dwordx4 coalesced loads per k-step, double-buffered) -> LDS.
// Phase 2: barrier-free wave-per-edge GRU + att2 dot + att1 scalar tables.
__global__ __launch_bounds__(256) void att_kernel(
    const float* __restrict__ hidden_rel,
    const float4* __restrict__ wP,    // [64][4][256] float4; mats 1..3 = w_hh r/z/n
    const float* __restrict__ b_hh,
    const float* __restrict__ gi,     // [NREL][768] (includes b_ih)
    const float* __restrict__ att2w, const float* __restrict__ att2b,
    const int* __restrict__ facts,
    const int* __restrict__ bin_off, const int* __restrict__ bin_edges,
    const float* __restrict__ qdot, const float* __restrict__ sn_m,
    const float* __restrict__ sr_m, const float* __restrict__ se,
    const float* __restrict__ st,   const float* __restrict__ consts,
    float* __restrict__ attention){
  __shared__ float gh_s[16][776];   // 49664 B
  int tile0 = blockIdx.x*16;
  int t = threadIdx.x;

  // ---- phase 1: thread t computes dims {t, t+256, t+512} for 16 nodes
  float acc[3][16];
  #pragma unroll
  for (int q = 0; q < 3; ++q)
    #pragma unroll
    for (int p = 0; p < 16; ++p) acc[q][p] = 0.f;

  float4 w1 = wP[256 + t], w2 = wP[512 + t], w3 = wP[768 + t];
  for (int kb = 0; kb < 64; ++kb){
    int kbn = (kb + 1) & 63;
    int nb = (kbn*4)*256 + t;
    float4 nw1 = wP[nb + 256], nw2 = wP[nb + 512], nw3 = wP[nb + 768];
    int k = kb*4;
    #pragma unroll
    for (int p = 0; p < 16; ++p){
      float4 a = *(const float4*)&hidden_rel[(size_t)(tile0+p)*256 + k];  // uniform -> s_load
      acc[0][p] += w1.x*a.x + w1.y*a.y + w1.z*a.z + w1.w*a.w;
      acc[1][p] += w2.x*a.x + w2.y*a.y + w2.z*a.z + w2.w*a.w;
      acc[2][p] += w3.x*a.x + w3.y*a.y + w3.z*a.z + w3.w*a.w;
    }
    w1 = nw1; w2 = nw2; w3 = nw3;
  }
  #pragma unroll
  for (int q = 0; q < 3; ++q){
    float bv = b_hh[t + 256*q];
    #pragma unroll
    for (int p = 0; p < 16; ++p)
      gh_s[p][t + 256*q] = acc[q][p] + bv;
  }
  __syncthreads();

  // ---- phase 2: wave per edge, lane l covers dims 4l..4l+3
  int wv = t >> 6, l = t & 63;
  int o0 = bin_off[blockIdx.x], o1 = bin_off[blockIdx.x + 1];
  int d0 = 4*l;
  float4 a2 = *(const float4*)&att2w[d0];
  float c1 = consts[0];
  float a2b = att2b[0];
  for (int idx = o0 + wv; idx < o1; idx += 4){
    int e  = bin_edges[idx];
    int b  = facts[e*6+0], n = facts[e*6+1], r = facts[e*6+3];
    int t_ = facts[e*6+4], ts_ = facts[e*6+5];
    int nl = n - tile0;
    float4 ghr = *(const float4*)&gh_s[nl][d0];
    float4 ghz = *(const float4*)&gh_s[nl][256+d0];
    float4 ghn = *(const float4*)&gh_s[nl][512+d0];
    const float* girow = gi + (size_t)r*768;
    float4 gir = *(const float4*)&girow[d0];
    float4 giz = *(const float4*)&girow[256+d0];
    float4 gin = *(const float4*)&girow[512+d0];
    float4 hp  = *(const float4*)&hidden_rel[(size_t)n*256 + d0];
    float partial;
    {
      float rg = sigm(gir.x + ghr.x), zg = sigm(giz.x + ghz.x);
      float ng = tanhf(gin.x + rg*ghn.x);
      partial = a2.x * ((1.f - zg)*ng + zg*hp.x);
    }{
      float rg = sigm(gir.y + ghr.y), zg = sigm(giz.y + ghz.y);
      float ng = tanhf(gin.y + rg*ghn.y);
      partial += a2.y * ((1.f - zg)*ng + zg*hp.y);
    }{
      float rg = sigm(gir.z + ghr.z), zg = sigm(giz.z + ghz.z);
      float ng = tanhf(gin.z + rg*ghn.z);
      partial += a2.z * ((1.f - zg)*ng + zg*hp.z);
    }{
      float rg = sigm(gir.w + ghr.w), zg = sigm(giz.w + ghz.w);
      float ng = tanhf(gin.w + rg*ghn.w);
      partial += a2.w * ((1.f - zg)*ng + zg*hp.w);
    }
    #pragma unroll
    for (int o = 32; o > 0; o >>= 1) partial += __shfl_xor(partial, o);
    if (l == 0){
      float att2 = sigm(partial + a2b);
      float x1 = qdot[b] + sn_m[n] + sr_m[r] + se[t_] + st[ts_] + c1;
      attention[e] = 0.5f*(sigm(x1) + att2);
    }
  }
}

// ---------------------------------------------------------------- stage 2: per-batch top-64
__global__ __launch_bounds__(256) void topk_kernel(
    const int* __restrict__ facts, const float* __restrict__ attention,
    const float* __restrict__ att_agg,
    int* __restrict__ sel_edge, float* __restrict__ att_norm,
    unsigned* __restrict__ skey, int* __restrict__ Ub){
  __shared__ float sa[512];
  __shared__ int   si[512];
  __shared__ unsigned sk[64];
  __shared__ int cnt;
  int b = blockIdx.x, tid = threadIdx.x;
  sa[tid] = -1.f; sa[tid+256] = -1.f;
  si[tid] = 0x7fffffff; si[tid+256] = 0x7fffffff;
  if (tid == 0) cnt = 0;
  __syncthreads();
  for (int e = tid; e < E_N; e += 256){
    if (facts[e*6] == b){
      int p = atomicAdd(&cnt, 1);
      if (p < 512){ sa[p] = attention[e]; si[p] = e; }
    }
  }
  __syncthreads();
  // bitonic sort: attention desc, edge index asc (matches stable lexsort)
  for (int k = 2; k <= 512; k <<= 1){
    for (int j = k >> 1; j > 0; j >>= 1){
      for (int i0 = tid; i0 < 512; i0 += 256){
        int l = i0 ^ j;
        if (l > i0){
          float ai = sa[i0], al = sa[l];
          int   ii = si[i0], il = si[l];
          bool lFirst = (al > ai) || (al == ai && il < ii);
          bool up = ((i0 & k) == 0);
          if (up ? lFirst : !lFirst){
            sa[i0] = al; sa[l] = ai; si[i0] = il; si[l] = ii;
          }
        }
      }
      __syncthreads();
    }
  }
  if (tid < 64){
    int e = si[tid];
    bool valid = (e != 0x7fffffff);
    if (!valid) e = 0;
    int n = facts[e*6+1];
    float a = valid ? sa[tid]*att_agg[n] : 0.f;
    float den = a;
    for (int o = 32; o > 0; o >>= 1) den += __shfl_down(den, o);
    den = __shfl(den, 0);
    float norm = (den != 0.f) ? a/den : 0.f;
    sel_edge[b*64 + tid] = e;
    att_norm[b*64 + tid] = norm;
    int t_ = facts[e*6+4], ts_ = facts[e*6+5];
    unsigned key = (((unsigned)t_) << 11) | (unsigned)ts_;
    sk[tid] = (key << 6) | (unsigned)tid;
  }
  __syncthreads();
  for (int k = 2; k <= 64; k <<= 1){
    for (int j = k >> 1; j > 0; j >>= 1){
      unsigned nv = 0; bool act = tid < 64;
      if (act){
        unsigned mine = sk[tid], other = sk[tid ^ j];
        bool up = ((tid & k) == 0);
        bool keepmin = (up == ((tid & j) == 0));
        nv = keepmin ? (mine < other ? mine : other) : (mine > other ? mine : other);
      }
      __syncthreads();
      if (act) sk[tid] = nv;
      __syncthreads();
    }
  }
  if (tid < 64){
    unsigned kk = sk[tid];
    skey[b*64 + tid] = kk;
    bool head = (tid == 0) || ((kk >> 6) != (sk[tid-1] >> 6));
    unsigned long long bal = __ballot(head);
    if (tid == 0) Ub[b] = __popcll(bal);
  }
}

__global__ void offs_scan_kernel(const int* __restrict__ Ub, int* __restrict__ offs){
  int lane = threadIdx.x;  // 64 threads, 1 block
  int run = 0;
  for (int base = 0; base < 256; base += 64){
    int orig = Ub[base + lane];
    int v = orig;
    for (int o = 1; o < 64; o <<= 1){ int t = __shfl_up(v, o); if (lane >= o) v += t; }
    offs[base + lane] = run + v - orig;
    run += __shfl(v, 63);
  }
  if (lane == 0) offs[256] = run;
}

__global__ void emit_kernel(const unsigned* __restrict__ skey, const int* __restrict__ offs,
                            int* __restrict__ us, int* __restrict__ tails,
                            float* __restrict__ out_tail){
  int b = blockIdx.x, tid = threadIdx.x;  // block of 64
  unsigned kk = skey[b*64 + tid];
  bool head = (tid == 0) || ((kk >> 6) != (skey[b*64 + tid - 1] >> 6));
  unsigned long long bal = __ballot(head);
  unsigned long long mask_le = (tid == 63) ? ~0ull : ((1ull << (tid+1)) - 1ull);
  int ulocal = __popcll(bal & mask_le) - 1;
  int u = offs[b] + ulocal;
  us[b*64 + tid] = u;
  if (head){
    unsigned key = kk >> 6;
    int t_ = (int)(key >> 11), ts_ = (int)(key & 2047u);
    tails[u*3+0] = b; tails[u*3+1] = t_; tails[u*3+2] = ts_;
    out_tail[u*3+0] = (float)b;
    out_tail[u*3+1] = (float)t_;
    out_tail[u*3+2] = (float)ts_;
  }
}

// ---------------------------------------------------------------- selected-edge vectors
// k-major broadcast GEMV: thread t = output dim, 8 edges per block.
__global__ __launch_bounds__(256) void sel_kernel(
    const unsigned* __restrict__ skey, const int* __restrict__ sel_edge,
    const float* __restrict__ att_norm, const int* __restrict__ facts,
    const float* __restrict__ hidden_node, const float* __restrict__ hidden_rel,
    const float4* __restrict__ wP,   // [64][4][256] float4
    const float* __restrict__ msg_r, const float* __restrict__ gi,
    const float* __restrict__ b_hh,
    float* __restrict__ msg_sel, float* __restrict__ hrn_sel){
  __shared__ int n_s[8], r_s[8];
  __shared__ float av_s[8];
  int base = blockIdx.x*8;
  int t = threadIdx.x;
  if (t < 8){
    int gs = base + t;
    int b = gs >> 6, i = gs & 63;
    int j = (int)(skey[(size_t)b*64 + i] & 63u);
    int s = b*64 + j;
    int e = sel_edge[s];
    n_s[t] = facts[e*6+1];
    r_s[t] = facts[e*6+3];
    av_s[t] = att_norm[s];
  }
  __syncthreads();

  float acc[4][8];
  #pragma unroll
  for (int q = 0; q < 4; ++q)
    #pragma unroll
    for (int e = 0; e < 8; ++e) acc[q][e] = 0.f;

  float4 w0 = wP[t], w1 = wP[256 + t], w2 = wP[512 + t], w3 = wP[768 + t];
  for (int kb = 0; kb < 64; ++kb){
    int kbn = (kb + 1) & 63;
    int nb = (kbn*4)*256 + t;
    float4 nw0 = wP[nb], nw1 = wP[nb + 256], nw2 = wP[nb + 512], nw3 = wP[nb + 768];
    int k = kb*4;
    #pragma unroll
    for (int e = 0; e < 8; ++e){
      float4 an = *(const float4*)&hidden_node[(size_t)n_s[e]*256 + k];  // uniform
      float4 ah = *(const float4*)&hidden_rel[(size_t)n_s[e]*256 + k];   // uniform
      acc[0][e] += w0.x*an.x + w0.y*an.y + w0.z*an.z + w0.w*an.w;
      acc[1][e] += w1.x*ah.x + w1.y*ah.y + w1.z*ah.z + w1.w*ah.w;
      acc[2][e] += w2.x*ah.x + w2.y*ah.y + w2.z*ah.z + w2.w*ah.w;
      acc[3][e] += w3.x*ah.x + w3.y*ah.y + w3.z*ah.z + w3.w*ah.w;
    }
    w0 = nw0; w1 = nw1; w2 = nw2; w3 = nw3;
  }

  float bhr = b_hh[t], bhz = b_hh[256+t], bhn = b_hh[512+t];
  #pragma unroll
  for (int e = 0; e < 8; ++e){
    int r = r_s[e]; float a = av_s[e];
    const float* girow = gi + (size_t)r*768;
    float msgv = acc[0][e] + msg_r[(size_t)r*256 + t];
    float rg = sigm(girow[t]      + acc[1][e] + bhr);
    float zg = sigm(girow[256+t]  + acc[2][e] + bhz);
    float ng = tanhf(girow[512+t] + rg*(acc[3][e] + bhn));
    float hp = hidden_rel[(size_t)n_s[e]*256 + t];
    float hrn = (1.f - zg)*ng + zg*hp;
    size_t o = (size_t)(base + e)*256 + t;
    msg_sel[o] = a*msgv;
    hrn_sel[o] = a*hrn;
  }
}

// ---------------------------------------------------------------- deterministic segment sums
__global__ __launch_bounds__(256) void segsum_kernel(
    const unsigned* __restrict__ skey, const int* __restrict__ us,
    const float* __restrict__ att_norm,
    const float* __restrict__ msg_sel, const float* __restrict__ hrn_sel,
    float* __restrict__ msg_agg, float* __restrict__ out_hrel,
    float* __restrict__ out_aagg){
  int b = blockIdx.x, d = threadIdx.x;
  float accm = 0.f, acch = 0.f, acca = 0.f;
  int ucur = -1;
  for (int i = 0; i < 64; ++i){
    int u = us[b*64 + i];
    if (u != ucur){
      if (ucur >= 0){
        msg_agg[(size_t)ucur*256 + d] = accm;
        out_hrel[(size_t)ucur*256 + d] = acch;
        if (d == 0) out_aagg[ucur] = acca;
      }
      ucur = u; accm = 0.f; acch = 0.f; acca = 0.f;
    }
    size_t o = (size_t)(b*64 + i)*256 + d;
    accm += msg_sel[o];
    acch += hrn_sel[o];
    int j = (int)(skey[b*64 + i] & 63u);
    acca += att_norm[b*64 + j];
  }
  if (ucur >= 0){
    msg_agg[(size_t)ucur*256 + d] = accm;
    out_hrel[(size_t)ucur*256 + d] = acch;
    if (d == 0) out_aagg[ucur] = acca;
  }
}

// ---------------------------------------------------------------- final linear
__global__ __launch_bounds__(256) void final_kernel(
    const float* __restrict__ msg_agg, const int* __restrict__ tails,
    const float* __restrict__ ent_t, const float* __restrict__ time_t,
    const float* __restrict__ w_h, const float* __restrict__ b_h,
    float* __restrict__ out_hn){
  __shared__ float x_s[16][520];
  int tile0 = blockIdx.x*16;
  for (int idx = threadIdx.x; idx < 16*512; idx += 256){
    int i = idx >> 9, k = idx & 511;
    int u = tile0 + i;
    float v;
    if (k < 256) v = msg_agg[(size_t)u*256 + k];
    else {
      int kk = k - 256;
      v = ent_t[(size_t)tails[u*3+1]*256 + kk] + time_t[(size_t)tails[u*3+2]*256 + kk];
    }
    x_s[i][k] = v;
  }
  __syncthreads();
  int d = threadIdx.x;
  const float* wrow = w_h + (size_t)d*512;
  float bv = b_h[d];
  float acc[16];
  #pragma unroll
  for (int i = 0; i < 16; ++i) acc[i] = bv;
  for (int k = 0; k < 512; k += 4){
    float4 w = *(const float4*)(wrow + k);
    #pragma unroll
    for (int i = 0; i < 16; ++i){
      float4 a = *(const float4*)&x_s[i][k];
      acc[i] += w.x*a.x + w.y*a.y + w.z*a.z + w.w*a.w;
    }
  }
  #pragma unroll
  for (int i = 0; i < 16; ++i)
    out_hn[(size_t)(tile0+i)*256 + d] = acc[i];
}

// ================================================================ launcher
extern "C" void kernel_launch(void* const* d_in, const int* in_sizes, int n_in,
                              void* d_out, int out_size, void* d_ws, size_t ws_size,
                              hipStream_t stream){
  const float* query_emd   = (const float*)d_in[1];
  const int*   facts       = (const int*)  d_in[2];
  const float* ent_emd     = (const float*)d_in[3];
  const float* rel_emd     = (const float*)d_in[4];
  const float* hidden_node = (const float*)d_in[5];
  const float* hidden_rel  = (const float*)d_in[6];
  const float* att_agg     = (const float*)d_in[8];
  const float* time_emd    = (const float*)d_in[9];
  const float* w_msg       = (const float*)d_in[11];
  const float* b_msg       = (const float*)d_in[12];
  const float* att1w       = (const float*)d_in[13];
  const float* att1b       = (const float*)d_in[14];
  const float* att2w       = (const float*)d_in[15];
  const float* att2b       = (const float*)d_in[16];
  const float* w_h         = (const float*)d_in[17];
  const float* b_h         = (const float*)d_in[18];
  const float* lets_w      = (const float*)d_in[19];
  const float* lets_b      = (const float*)d_in[20];
  const float* lrts_w      = (const float*)d_in[21];
  const float* lrts_b      = (const float*)d_in[22];
  const float* w_ih        = (const float*)d_in[25];
  const float* w_hh        = (const float*)d_in[26];
  const float* b_ih        = (const float*)d_in[27];
  const float* b_hh        = (const float*)d_in[28];

  // ---- workspace carve
  char* p = (char*)d_ws;
  auto alloc = [&](size_t bytes) -> void* {
    void* r = (void*)p; p += (bytes + 255) & ~(size_t)255; return r;
  };
  // zero-region (contiguous): bin_cnt, bin_cur, tails, msg_agg
  int* bin_cnt  = (int*)alloc(3136*4);
  int* bin_cur  = (int*)alloc(3136*4);
  int* tails    = (int*)alloc((size_t)M_OUT*3*4);
  float* msg_agg= (float*)alloc((size_t)M_OUT*256*4);
  size_t zero_words = (3136*4 + 3136*4 + (size_t)M_OUT*3*4 + (size_t)M_OUT*256*4) / 4;
  int* bin_off  = (int*)alloc(3136*4);
  int* bin_edges= (int*)alloc(E_N*4);
  float* attention = (float*)alloc(E_N*4);
  float* qdot   = (float*)alloc(256*4);
  float* sn_m   = (float*)alloc(NPREV*4);
  float* se     = (float*)alloc(NENT*4);
  float* st     = (float*)alloc(NTIME*4);
  float* sr_m   = (float*)alloc(NREL*4);
  float* wm1a   = (float*)alloc(256*4);
  float* ve     = (float*)alloc(256*4);
  float* vts    = (float*)alloc(256*4);
  float* consts = (float*)alloc(8*4);
  float* hr2    = (float*)alloc((size_t)NREL*256*4);
  float* msg_r  = (float*)alloc((size_t)NREL*256*4);
  float* gi     = (float*)alloc((size_t)NREL*768*4);
  float* time_t = (float*)alloc((size_t)NTIME*256*4);
  float* ent_t  = (float*)alloc((size_t)NENT*256*4);
  float4* wP    = (float4*)alloc((size_t)65536*16);   // packed weights
  int* sel_edge = (int*)alloc(M_OUT*4);
  float* att_nrm= (float*)alloc(M_OUT*4);
  unsigned* skey= (unsigned*)alloc(M_OUT*4);
  int* Ub       = (int*)alloc(256*4);
  int* offs     = (int*)alloc(257*4);
  int* us       = (int*)alloc(M_OUT*4);
  float* msg_sel= (float*)alloc((size_t)M_OUT*256*4);
  float* hrn_sel= (float*)alloc((size_t)M_OUT*256*4);
  (void)ws_size; (void)in_sizes; (void)n_in;

  // f32 output layout: [tail_nodes 16384*3 | hidden_node_new 16384*256 |
  //                     hidden_rel_out 16384*256 | att_agg_new 16384]
  float* out_f     = (float*)d_out;
  float* out_tail  = out_f;
  float* out_hn    = out_f + (size_t)M_OUT*3;
  float* out_hrel  = out_f + (size_t)M_OUT*3 + (size_t)M_OUT*256;
  float* out_aagg  = out_f + (size_t)M_OUT*3 + (size_t)2*M_OUT*256;

  // ---- zeroing
  zero_kernel<<<(out_size+255)/256, 256, 0, stream>>>((unsigned*)d_out, out_size);
  zero_kernel<<<((int)zero_words+255)/256, 256, 0, stream>>>((unsigned*)bin_cnt, (int)zero_words);

  // ---- packs + tiny precomputes
  pack_w_kernel<<<256, 256, 0, stream>>>(w_msg, w_hh, wP);
  matvec_fused<<<4, 256, 0, stream>>>(w_msg, lets_w, lets_b, att1w, att1b, wm1a, ve, vts, consts);

  // ---- per-relation / per-entity / per-time tables
  tile_linear<1><<<(NREL+15)/16, 256, 0, stream>>>(rel_emd, 256, lrts_w, 256, 0, lrts_b, hr2, 256, NREL);
  tile_linear<1><<<(NREL+15)/16, 256, 0, stream>>>(hr2, 256, w_msg, 512, 256, b_msg, msg_r, 256, NREL);
  tile_linear<3><<<(NREL+15)/16, 256, 0, stream>>>(hr2, 256, w_ih, 256, 0, b_ih, gi, 768, NREL);
  tile_linear<1><<<(NTIME+15)/16, 256, 0, stream>>>(time_emd, 256, lets_w, 512, 256, (const float*)nullptr, time_t, 256, NTIME);
  tile_linear<1><<<(NENT+15)/16, 256, 0, stream>>>(ent_emd, 256, lets_w, 512, 0, lets_b, ent_t, 256, NENT);

  // ---- scalar tables (fused; seg4 needs msg_r -> after tile_linear msg_r)
  {
    int total_rows = B_N + NPREV + NENT + NTIME + NREL;
    int blocks = (total_rows*64 + 255)/256;
    rows_dot_multi<<<blocks, 256, 0, stream>>>(
        query_emd, att1w, qdot, B_N,
        hidden_node, wm1a, sn_m, NPREV,
        ent_emd, ve, se, NENT,
        time_emd, vts, st, NTIME,
        msg_r, att1w+256, sr_m, NREL);
  }

  // ---- bins by tile
  hist_kernel<<<(E_N+255)/256, 256, 0, stream>>>(facts, bin_cnt);
  bin_scan_kernel<<<1, 64, 0, stream>>>(bin_cnt, bin_off, bin_cur);
  scatter_kernel<<<(E_N+255)/256, 256, 0, stream>>>(facts, bin_cur, bin_edges);

  // ---- stage 1: attention per edge
  att_kernel<<<NTILE, 256, 0, stream>>>(hidden_rel, wP, b_hh, gi, att2w, att2b,
      facts, bin_off, bin_edges, qdot, sn_m, sr_m, se, st, consts, attention);

  // ---- stage 2: selection, unique, aggregation
  topk_kernel<<<B_N, 256, 0, stream>>>(facts, attention, att_agg, sel_edge, att_nrm, skey, Ub);
  offs_scan_kernel<<<1, 64, 0, stream>>>(Ub, offs);
  emit_kernel<<<B_N, 64, 0, stream>>>(skey, offs, us, tails, out_tail);
  sel_kernel<<<M_OUT/8, 256, 0, stream>>>(skey, sel_edge, att_nrm, facts,
      hidden_node, hidden_rel, wP, msg_r, gi, b_hh, msg_sel, hrn_sel);
  segsum_kernel<<<B_N, 256, 0, stream>>>(skey, us, att_nrm, msg_sel, hrn_sel,
      msg_agg, out_hrel, out_aagg);
  final_kernel<<<M_OUT/16, 256, 0, stream>>>(msg_agg, tails, ent_t, time_t, w_h, b_h, out_hn);
}